// Round 16
// baseline (359.573 us; speedup 1.0000x reference)
//
#include <hip/hip_runtime.h>
#include <hip/hip_bf16.h>

typedef __hip_bfloat16 bf16;

#define BB 16
#define LL 512
#define DD 512
#define NHH 8
#define HDD 64
#define TT 17
#define MM (BB*LL)
#define RCH 8
#define RCK 65

typedef __attribute__((ext_vector_type(8))) short bfrag;
typedef __attribute__((ext_vector_type(4))) float ffrag;
typedef __attribute__((ext_vector_type(8))) unsigned short us8;

struct Params {
  const int* tokens;
  const float* emb;
  const float *sat_qw, *sat_qb, *sat_kw, *sat_kb, *sat_vw, *sat_vb, *sat_ow, *sat_ob;
  const float *rel_qw, *rel_qb, *rel_kw, *rel_kb, *rel_vw, *rel_vb, *rel_ow, *rel_ob;
  const float *ln_sat_w, *ln_sat_b, *ln_rel_w, *ln_rel_b, *ofc_w, *ofc_b;
  bf16 *ebf, *qkv, *kvbuf, *KeVe, *qbuf, *ctxbf, *WtAll, *WtO, *WtLog;
  float *s, *KsVs, *qr, *Ksr, *Vsr, *mpart, *pws, *out;
};

static __device__ __forceinline__ void gld16(const void* g, void* l){
  __builtin_amdgcn_global_load_lds((const __attribute__((address_space(1))) void*)g,
                                   (__attribute__((address_space(3))) void*)l, 16, 0, 0);
}
static __device__ __forceinline__ float us2f(unsigned short u){
  unsigned int v = ((unsigned int)u) << 16;
  float f; __builtin_memcpy(&f, &v, 4); return f;
}
static __device__ __forceinline__ float hsum8(float v){
  v += __shfl_xor(v, 1); v += __shfl_xor(v, 2); v += __shfl_xor(v, 4);
  return v;
}

// ---------------- init: embed+mean partials (u<256) | weight prep ----------------
__global__ __launch_bounds__(256) void k_init(Params P){
  __shared__ __align__(16) char sm[8192];
  int u = blockIdx.x, t = threadIdx.x;
  if (u < 256){
    int* toks = (int*)sm;
    int b = u >> 4, lc = u & 15;
    if (t < 32) toks[t] = P.tokens[b*LL + lc*32 + t];
    __syncthreads();
    bf16* eb = P.ebf + ((size_t)b*LL + lc*32)*DD;
    for (int d = t; d < DD; d += 256){
      float acc = 0.f;
      #pragma unroll 4
      for (int l = 0; l < 32; l++){
        float v = P.emb[(size_t)toks[l]*DD + d];
        eb[(size_t)l*DD + d] = __float2bfloat16(v);
        acc += v;
      }
      P.mpart[(size_t)u*DD + d] = acc;
    }
    return;
  }
  int w = u - 256;
  int z = w >> 8, xy = w & 255;
  int tx = t & 31, ty = t >> 5;
  if (z == 6){
    int i = (xy << 8) + t;
    int row = i >> 9, k = i & 511;
    P.WtLog[i] = __float2bfloat16(row < TT ? P.ofc_w[(size_t)k*TT + row] : 0.f);
    return;
  }
  float (*tile)[33] = (float(*)[33])sm;
  const float* in = (z==0)?P.sat_qw:(z==1)?P.sat_kw:(z==2)?P.sat_vw:
                    (z==3)?P.rel_kw:(z==4)?P.rel_vw:P.sat_ow;
  bf16* out = (z<5) ? (P.WtAll + (size_t)z*512*512) : P.WtO;
  int bx = (xy & 15)*32, by = (xy >> 4)*32;
  #pragma unroll
  for (int j = 0; j < 32; j += 8)
    tile[ty + j][tx] = in[(size_t)(by + ty + j)*DD + bx + tx];
  __syncthreads();
  #pragma unroll
  for (int j = 0; j < 32; j += 8)
    out[(size_t)(bx + ty + j)*DD + by + tx] = __float2bfloat16(tile[tx][ty + j]);
}

// ---------------- mean stage 2: s[16,512] ----------------
__global__ __launch_bounds__(256) void k_mean2(Params P){
  int i = blockIdx.x*256 + threadIdx.x;   // 8192
  int b = i >> 9, d = i & 511;
  float acc = 0.f;
  #pragma unroll
  for (int c = 0; c < 16; c++) acc += P.mpart[(size_t)(b*16 + c)*DD + d];
  P.s[i] = acc * (1.0f/LL);
}

// ---------------- s-projection unit (split-k, A read from global s-like buffer) ----------------
static __device__ void sproj_unit(int u, int t, char* sm, const float* A,
    const float* W0, const float* W1, const float* W2, const float* W3, const float* W4,
    const float* bias0, const float* bias1, const float* bias2, const float* bias3,
    const float* bias4,
    float* O0, float* O1, float* O2, float* O3, float* O4,
    int ldc0, int ldc1, int ldc2, int ldc3, int ldc4){
  float (*part)[32][17] = (float(*)[32][17])sm;
  int n = t & 31, kg = t >> 5;
  int wi = u >> 4, ch = u & 15;
  const float* W  = (wi==0)?W0:(wi==1)?W1:(wi==2)?W2:(wi==3)?W3:W4;
  const float* bs = (wi==0)?bias0:(wi==1)?bias1:(wi==2)?bias2:(wi==3)?bias3:bias4;
  float* O  = (wi==0)?O0:(wi==1)?O1:(wi==2)?O2:(wi==3)?O3:O4;
  int ldc   = (wi==0)?ldc0:(wi==1)?ldc1:(wi==2)?ldc2:(wi==3)?ldc3:ldc4;
  int col = ch*32 + n;
  float acc[16];
  #pragma unroll
  for (int m = 0; m < 16; m++) acc[m] = 0.f;
  const float* Wp = W + (size_t)(kg*64)*512 + col;
  const float* Ap = A + kg*64;
  for (int k = 0; k < 64; k++){
    float w = Wp[(size_t)k*512];
    #pragma unroll
    for (int m = 0; m < 16; m++) acc[m] = fmaf(Ap[m*512 + k], w, acc[m]);
  }
  #pragma unroll
  for (int m = 0; m < 16; m++) part[kg][n][m] = acc[m];
  __syncthreads();
  for (int o = t; o < 512; o += 256){
    int m = o >> 5, nn = o & 31;
    float v = 0.f;
    #pragma unroll
    for (int g = 0; g < 8; g++) v += part[g][nn][m];
    O[(size_t)m*ldc + ch*32 + nn] = v + bs[ch*32 + nn];
  }
}

// ---------------- MFMA GEMM unit (conflict-free swizzled LDS, XCD rows) ----------------
static __device__ void gemm_unit(int id, int t, char* sm,
    const bf16* __restrict__ A, const bf16* __restrict__ Wt,
    const float* b0, const float* b1, const float* b2, const float* b3, const float* b4,
    bf16* D0, int ld0, bf16* D1, int ld1, int split){
  const int K = 512;
  bf16* As = (bf16*)sm;
  bf16* Bs = (bf16*)(sm + 8192);
  int wave = t >> 6, lane = t & 63;
  int bm = (((id & 7) << 3) | ((id >> 3) & 7)) * 128;
  int bn = (id >> 6) * 128;
  int wm = (wave & 1) * 64, wn = (wave >> 1) * 64;
  ffrag acc[4][4];
  #pragma unroll
  for (int i = 0; i < 4; i++)
    #pragma unroll
    for (int j = 0; j < 4; j++) acc[i][j] = (ffrag){0.f,0.f,0.f,0.f};

  int srow = t >> 2;
  // bank-conflict-free swizzle (r13/r15: SQ_LDS_BANK_CONFLICT = 0, verified)
  int scol = ((((t & 3) - ((t >> 3) & 3)) & 3)) * 8;
  const bf16* gA = A  + (size_t)(bm + srow)*K + scol;
  const bf16* gB = Wt + (size_t)(bn + srow)*K + scol;
  char* lA = (char*)As + 16*t;
  char* lB = (char*)Bs + 16*t;
  int q = lane >> 4, r = lane & 15;
  int cs = (((q + (r >> 1)) & 3)) * 8;

  for (int k0 = 0; k0 < K; k0 += 32){
    gld16(gA + k0,          lA);
    gld16(gA + 64*K + k0,   lA + 4096);
    gld16(gB + k0,          lB);
    gld16(gB + 64*K + k0,   lB + 4096);
    __syncthreads();
    bfrag af[4], bfv[4];
    #pragma unroll
    for (int i = 0; i < 4; i++){
      af[i]  = *(const bfrag*)(As + (wm + i*16 + r)*32 + cs);
      bfv[i] = *(const bfrag*)(Bs + (wn + i*16 + r)*32 + cs);
    }
    #pragma unroll
    for (int i = 0; i < 4; i++)
      #pragma unroll
      for (int j = 0; j < 4; j++)
        acc[i][j] = __builtin_amdgcn_mfma_f32_16x16x32_bf16(af[i], bfv[j], acc[i][j], 0, 0, 0);
    __syncthreads();
  }
  #pragma unroll
  for (int i = 0; i < 4; i++){
    #pragma unroll
    for (int j = 0; j < 4; j++){
      int row = bm + wm + i*16 + q*4;
      int col = bn + wn + j*16 + r;
      const float* bp = (col < 512) ? b0 : (col < 1024) ? b1 :
                        (col < 1536) ? b2 : (col < 2048) ? b3 : b4;
      float bias = bp[col & 511];
      bf16* D; int ld;
      if (col < split){ D = D0 + (size_t)row*ld0 + col;         ld = ld0; }
      else            { D = D1 + (size_t)row*ld1 + (col-split); ld = ld1; }
      #pragma unroll
      for (int g = 0; g < 4; g++)
        D[(size_t)g*ld] = __float2bfloat16(acc[i][j][g] + bias);
    }
  }
}

// ---------------- merged launch: QKV-c0 GEMM (768) + c0 s-projections (80) ----------------
// Safe merge (r14 lesson): sproj split-k blocks (~5us) << gemm duration (~30us).
__global__ __launch_bounds__(256) void k_qkvsp(Params P){
  __shared__ __align__(16) char sm[17408];
  int u = blockIdx.x, t = threadIdx.x;
  if (u < 768)
    gemm_unit(u, t, sm, P.ebf, P.WtAll,
              P.sat_qb, P.sat_kb, P.sat_vb, P.sat_vb, P.sat_vb,
              P.qbuf, 512, P.KeVe, 1024, 512);
  else
    sproj_unit(u - 768, t, sm, P.s,
               P.sat_kw, P.sat_vw, P.rel_qw, P.rel_kw, P.rel_vw,
               P.sat_kb, P.sat_vb, P.rel_qb, P.rel_kb, P.rel_vb,
               P.KsVs, P.KsVs + 512, P.qr, P.Ksr, P.Vsr,
               1024, 1024, 512, 512, 512);
}

__global__ __launch_bounds__(256) void k_gemm(Params P, const bf16* A, const bf16* Wt,
    const float* b0, const float* b1, const float* b2, const float* b3, const float* b4,
    bf16* D0, int ld0, bf16* D1, int ld1, int split){
  __shared__ __align__(16) char sm[16384];
  gemm_unit(blockIdx.x, threadIdx.x, sm, A, Wt, b0, b1, b2, b3, b4, D0, ld0, D1, ld1, split);
}

__global__ __launch_bounds__(256) void k_sproj(Params P){
  __shared__ __align__(16) char sm[17408];
  // c1: only sat_k / sat_v needed (rel path dead after c0)
  sproj_unit(blockIdx.x, threadIdx.x, sm, P.s,
             P.sat_kw, P.sat_vw, P.sat_vw, P.sat_vw, P.sat_vw,
             P.sat_kb, P.sat_vb, P.sat_vb, P.sat_vb, P.sat_vb,
             P.KsVs, P.KsVs + 512, P.Vsr, P.Vsr, P.Vsr,
             1024, 1024, 512, 512, 512);
}

// ---------------- logits GEMM: masked to cols<32 (17 used) ----------------
__global__ __launch_bounds__(256) void k_logits(Params P){
  const int K = 512;
  __shared__ bf16 As[128*32];
  __shared__ bf16 Bs[128*32];
  int t = threadIdx.x;
  int wave = t >> 6, lane = t & 63;
  int bm = blockIdx.x * 128;
  int wm = (wave & 1) * 64, wn = (wave >> 1) * 64;
  ffrag acc[4][2];
  #pragma unroll
  for (int i = 0; i < 4; i++){ acc[i][0] = (ffrag){0,0,0,0}; acc[i][1] = (ffrag){0,0,0,0}; }
  int srow = t >> 2;
  int scol = ((((t & 3) - ((t >> 3) & 3)) & 3)) * 8;
  const bf16* gA = P.ebf + (size_t)(bm + srow)*K + scol;   // hbf aliases ebf
  const bf16* gB = P.WtLog + (size_t)srow*K + scol;
  char* lA = (char*)As + 16*t;
  char* lB = (char*)Bs + 16*t;
  int q = lane >> 4, r = lane & 15;
  int cs = (((q + (r >> 1)) & 3)) * 8;

  for (int k0 = 0; k0 < K; k0 += 32){
    gld16(gA + k0,          lA);
    gld16(gA + 64*K + k0,   lA + 4096);
    gld16(gB + k0,          lB);
    gld16(gB + 64*K + k0,   lB + 4096);
    __syncthreads();
    if (wn == 0){
      bfrag bf0 = *(const bfrag*)(Bs + (r)*32 + cs);
      bfrag bf1 = *(const bfrag*)(Bs + (16 + r)*32 + cs);
      #pragma unroll
      for (int i = 0; i < 4; i++){
        bfrag af = *(const bfrag*)(As + (wm + i*16 + r)*32 + cs);
        acc[i][0] = __builtin_amdgcn_mfma_f32_16x16x32_bf16(af, bf0, acc[i][0], 0, 0, 0);
        acc[i][1] = __builtin_amdgcn_mfma_f32_16x16x32_bf16(af, bf1, acc[i][1], 0, 0, 0);
      }
    }
    __syncthreads();
  }
  if (wn == 0){
    #pragma unroll
    for (int i = 0; i < 4; i++)
      #pragma unroll
      for (int j = 0; j < 2; j++){
        int row = bm + wm + i*16 + q*4;
        int col = j*16 + r;
        if (col < TT){
          float bv = P.ofc_b[col];
          #pragma unroll
          for (int g = 0; g < 4; g++)
            P.out[(size_t)(row + g)*TT + col] = acc[i][j][g] + bv;
        }
      }
  }
}

// ---------------- sat attention: wave/token, us8 loads ----------------
__global__ __launch_bounds__(256)
void k_sat(Params P, const bf16* qp, int sq, const bf16* kp, const bf16* vp, int skv){
  int tok = blockIdx.x*4 + (threadIdx.x >> 6);
  int l = threadIdx.x & 63;
  int b = tok >> 9, li = tok & 511;
  int off = l*8;
  int t0 = (b << 9) | ((li + 1) & 511);
  int t2 = (b << 9) | (li == 0 ? 511 : 0);
  float qf[8];
  { us8 q8 = *(const us8*)(qp + (size_t)tok*sq + off);
    #pragma unroll
    for (int g = 0; g < 8; g++) qf[g] = us2f(q8[g]); }
  float sc[5];
  int rows[3] = {t0, tok, t2};
  #pragma unroll
  for (int j = 0; j < 3; j++){
    us8 k8 = *(const us8*)(kp + (size_t)rows[j]*skv + off);
    float a = 0.f;
    #pragma unroll
    for (int g = 0; g < 8; g++) a += qf[g]*us2f(k8[g]);
    sc[j] = hsum8(a) * 0.125f;
  }
  { us8 k8 = *(const us8*)(P.KeVe + (size_t)tok*1024 + off);
    float a = 0.f;
    #pragma unroll
    for (int g = 0; g < 8; g++) a += qf[g]*us2f(k8[g]);
    sc[3] = hsum8(a) * 0.125f; }
  { const float* ks = P.KsVs + (size_t)b*1024 + off;
    float4 f0 = *(const float4*)ks, f1 = *(const float4*)(ks + 4);
    float a = qf[0]*f0.x + qf[1]*f0.y + qf[2]*f0.z + qf[3]*f0.w
            + qf[4]*f1.x + qf[5]*f1.y + qf[6]*f1.z + qf[7]*f1.w;
    sc[4] = hsum8(a) * 0.125f; }
  float m = fmaxf(fmaxf(fmaxf(sc[0],sc[1]), fmaxf(sc[2],sc[3])), sc[4]);
  float pr[5], den = 0.f;
  #pragma unroll
  for (int j = 0; j < 5; j++){ pr[j] = __expf(sc[j]-m); den += pr[j]; }
  float inv = 1.0f/den;
  float o[8];
  #pragma unroll
  for (int g = 0; g < 8; g++) o[g] = 0.f;
  #pragma unroll
  for (int j = 0; j < 3; j++){
    us8 v8 = *(const us8*)(vp + (size_t)rows[j]*skv + off);
    #pragma unroll
    for (int g = 0; g < 8; g++) o[g] += pr[j]*us2f(v8[g]);
  }
  { us8 v8 = *(const us8*)(P.KeVe + (size_t)tok*1024 + 512 + off);
    #pragma unroll
    for (int g = 0; g < 8; g++) o[g] += pr[3]*us2f(v8[g]); }
  { const float* vs = P.KsVs + (size_t)b*1024 + 512 + off;
    float4 f0 = *(const float4*)vs, f1 = *(const float4*)(vs + 4);
    o[0] += pr[4]*f0.x; o[1] += pr[4]*f0.y; o[2] += pr[4]*f0.z; o[3] += pr[4]*f0.w;
    o[4] += pr[4]*f1.x; o[5] += pr[4]*f1.y; o[6] += pr[4]*f1.z; o[7] += pr[4]*f1.w; }
  bf16 ob[8];
  #pragma unroll
  for (int g = 0; g < 8; g++) ob[g] = __float2bfloat16(o[g]*inv);
  *(us8*)(P.ctxbf + (size_t)tok*DD + off) = *(const us8*)ob;
}

// ---------------- wave-per-row relu+LN (sat), bf16 ----------------
__global__ __launch_bounds__(256) void k_ln(Params P, const bf16* X, bf16* Y){
  int row = blockIdx.x*4 + (threadIdx.x >> 6);
  int lane = threadIdx.x & 63;
  int off = lane*8;
  us8 x8 = *(const us8*)(X + (size_t)row*DD + off);
  float v[8], sum = 0.f;
  #pragma unroll
  for (int g = 0; g < 8; g++){ v[g] = fmaxf(us2f(x8[g]), 0.f); sum += v[g]; }
  #pragma unroll
  for (int o = 32; o; o >>= 1) sum += __shfl_xor(sum, o);
  float u = sum * (1.0f/DD);
  float d[8], var = 0.f;
  #pragma unroll
  for (int g = 0; g < 8; g++){ d[g] = v[g] - u; var += d[g]*d[g]; }
  #pragma unroll
  for (int o = 32; o; o >>= 1) var += __shfl_xor(var, o);
  float inv = rsqrtf(var * (1.0f/DD) + 1e-12f);
  bf16 ob[8];
  #pragma unroll
  for (int g = 0; g < 8; g++)
    ob[g] = __float2bfloat16(P.ln_sat_w[off+g]*d[g]*inv + P.ln_sat_b[off+g]);
  *(us8*)(Y + (size_t)row*DD + off) = *(const us8*)ob;
}

// ---------------- rel attention partials ----------------
__global__ __launch_bounds__(256) void k_relp(Params P){
  __shared__ __align__(16) char sm[4096];
  int u = blockIdx.x, t = threadIdx.x;
  int ch = u & 7, hh = (u >> 3) & 7, b = u >> 6;
  float* qs   = (float*)sm;
  float* sc   = (float*)(sm + 256);
  float* red  = (float*)(sm + 1024);
  float (*part)[64] = (float(*)[64])(sm + 2048);
  int base = hh * HDD;
  int j0 = ch * RCK;
  int nk = min(513 - j0, RCK);
  if (t < 64) qs[t] = P.qr[(size_t)b*DD + base + t];
  __syncthreads();
  if (t < nk){
    int j = j0 + t;
    float a = 0.f;
    if (j == 0){
      const float* kr = P.Ksr + (size_t)b*DD + base;
      #pragma unroll
      for (int d = 0; d < 64; d += 4){
        float4 k4 = *(const float4*)(kr + d);
        float4 q4 = *(const float4*)(qs + d);
        a += q4.x*k4.x + q4.y*k4.y + q4.z*k4.z + q4.w*k4.w;
      }
    } else {
      const bf16* kr = P.kvbuf + ((size_t)b*LL + j - 1)*1024 + base;
      #pragma unroll
      for (int d = 0; d < 64; d += 8){
        us8 k8 = *(const us8*)(kr + d);
        #pragma unroll
        for (int g = 0; g < 8; g++) a += qs[d+g] * us2f(k8[g]);
      }
    }
    sc[t] = a * 0.125f;
  }
  __syncthreads();
  red[t] = (t < nk) ? sc[t] : -1e30f; __syncthreads();
  for (int st = 128; st; st >>= 1){ if (t < st) red[t] = fmaxf(red[t], red[t+st]); __syncthreads(); }
  float m = red[0]; __syncthreads();
  if (t < nk) sc[t] = __expf(sc[t] - m);
  __syncthreads();
  red[t] = (t < nk) ? sc[t] : 0.f; __syncthreads();
  for (int st = 128; st; st >>= 1){ if (t < st) red[t] += red[t+st]; __syncthreads(); }
  float l = red[0];
  int d = t & 63, c2 = t >> 6;
  float a = 0.f;
  for (int j = c2; j < nk; j += 4){
    int gj = j0 + j;
    float vv = (gj == 0) ? P.Vsr[(size_t)b*DD + base + d]
                         : __bfloat162float(P.kvbuf[((size_t)b*LL + gj - 1)*1024 + 512 + base + d]);
    a += sc[j] * vv;
  }
  part[c2][d] = a; __syncthreads();
  float* o = P.pws + (((size_t)(b*NHH + hh))*RCH + ch) * 66;
  if (t < 64) o[t] = part[0][t] + part[1][t] + part[2][t] + part[3][t];
  else if (t == 64) o[64] = m;
  else if (t == 65) o[65] = l;
}

// ---------------- rel tail pass A: combine + split-k out-proj (256 blocks) ----------------
// block = (b, 32-col chunk); writes rr (= reuse of qr, dead after k_relp)
__global__ __launch_bounds__(256) void k_reltail2(Params P){
  __shared__ float crs[512];
  __shared__ float part[8][33];
  int b = blockIdx.x >> 4, ch = blockIdx.x & 15;
  int t = threadIdx.x;
  for (int o = t; o < 512; o += 256){
    int hh = o >> 6, d = o & 63;
    const float* p = P.pws + ((size_t)(b*NHH + hh))*RCH*66;
    float M = -1e30f;
    #pragma unroll
    for (int c = 0; c < RCH; c++) M = fmaxf(M, p[c*66 + 64]);
    float den = 0.f, acc = 0.f;
    #pragma unroll
    for (int c = 0; c < RCH; c++){
      float w = __expf(p[c*66 + 64] - M);
      den += w * p[c*66 + 65];
      acc += w * p[c*66 + d];
    }
    crs[o] = acc / den;
  }
  __syncthreads();
  int n = t & 31, kg = t >> 5;
  int col = ch*32 + n;
  const float* Wp = P.rel_ow + (size_t)(kg*64)*512 + col;
  const float* cp = crs + kg*64;
  float a = 0.f;
  for (int k = 0; k < 64; k++) a = fmaf(cp[k], Wp[(size_t)k*512], a);
  part[kg][n] = a;
  __syncthreads();
  if (t < 32){
    float v = P.rel_ob[ch*32 + t];
    #pragma unroll
    for (int g = 0; g < 8; g++) v += part[g][t];
    P.qr[(size_t)b*DD + ch*32 + t] = v;   // rr aliases qr
  }
}

// ---------------- rel tail pass B: relu+LN (fp32, wave-per-row) -> s ----------------
__global__ __launch_bounds__(256) void k_lnrel(Params P){
  int row = blockIdx.x*4 + (threadIdx.x >> 6);   // 4 blocks x 4 rows
  int lane = threadIdx.x & 63;
  int off = lane*8;
  const float* x = P.qr + (size_t)row*DD + off;
  float4 f0 = *(const float4*)x, f1 = *(const float4*)(x + 4);
  float v[8] = {f0.x, f0.y, f0.z, f0.w, f1.x, f1.y, f1.z, f1.w};
  float sum = 0.f;
  #pragma unroll
  for (int g = 0; g < 8; g++){ v[g] = fmaxf(v[g], 0.f); sum += v[g]; }
  #pragma unroll
  for (int o = 32; o; o >>= 1) sum += __shfl_xor(sum, o);
  float u = sum * (1.0f/DD);
  float d[8], var = 0.f;
  #pragma unroll
  for (int g = 0; g < 8; g++){ d[g] = v[g] - u; var += d[g]*d[g]; }
  #pragma unroll
  for (int o = 32; o; o >>= 1) var += __shfl_xor(var, o);
  float inv = rsqrtf(var * (1.0f/DD) + 1e-12f);
  // s MUST be written — feeds the c1 KsVs projection (round-5 lesson).
  #pragma unroll
  for (int g = 0; g < 8; g++)
    P.s[(size_t)row*DD + off + g] = P.ln_rel_w[off+g]*d[g]*inv + P.ln_rel_b[off+g];
}

extern "C" void kernel_launch(void* const* d_in, const int* in_sizes, int n_in,
                              void* d_out, int out_size, void* d_ws, size_t ws_size,
                              hipStream_t stream) {
  Params P;
  P.tokens  = (const int*)  d_in[0];
  P.emb     = (const float*)d_in[4];
  P.sat_qw  = (const float*)d_in[5];  P.sat_qb = (const float*)d_in[6];
  P.sat_kw  = (const float*)d_in[7];  P.sat_kb = (const float*)d_in[8];
  P.sat_vw  = (const float*)d_in[9];  P.sat_vb = (const float*)d_in[10];
  P.sat_ow  = (const float*)d_in[11]; P.sat_ob = (const float*)d_in[12];
  P.rel_qw  = (const float*)d_in[13]; P.rel_qb = (const float*)d_in[14];
  P.rel_kw  = (const float*)d_in[15]; P.rel_kb = (const float*)d_in[16];
  P.rel_vw  = (const float*)d_in[17]; P.rel_vb = (const float*)d_in[18];
  P.rel_ow  = (const float*)d_in[19]; P.rel_ob = (const float*)d_in[20];
  P.ln_sat_w= (const float*)d_in[21]; P.ln_sat_b= (const float*)d_in[22];
  P.ln_rel_w= (const float*)d_in[23]; P.ln_rel_b= (const float*)d_in[24];
  P.ofc_w   = (const float*)d_in[25]; P.ofc_b  = (const float*)d_in[26];

  char* p = (char*)d_ws;
  auto alloc = [&](size_t bytes) -> char* {
    char* r = p; p += (bytes + 255) & ~(size_t)255; return r;
  };
  const size_t BIGH = (size_t)MM*DD*2;
  P.ebf   = (bf16*) alloc(BIGH);
  P.qkv   = (bf16*) alloc(3*BIGH);
  P.kvbuf = (bf16*) alloc(2*BIGH);
  P.KeVe  = (bf16*) alloc(2*BIGH);
  P.qbuf  = (bf16*) alloc(BIGH);
  P.ctxbf = (bf16*) alloc(BIGH);
  P.WtAll = (bf16*) alloc((size_t)2560*512*2);
  P.WtO   = (bf16*) alloc((size_t)512*512*2);
  P.WtLog = (bf16*) alloc((size_t)128*512*2);
  P.s     = (float*)alloc(BB*DD*4);
  P.KsVs  = (float*)alloc(BB*1024*4);
  P.qr    = (float*)alloc(BB*DD*4);
  P.Ksr   = (float*)alloc(BB*DD*4);
  P.Vsr   = (float*)alloc(BB*DD*4);
  P.mpart = (float*)alloc((size_t)256*DD*4);
  P.pws   = (float*)alloc((size_t)BB*NHH*RCH*66*4);
  P.out   = (float*)d_out;

  bf16* hbf  = P.ebf;   // h aliases e
  bf16* aout = P.qkv;   // out-proj scratch aliases qkv

  // 15 launches; no grid.sync (r13); no long-serial blocks in wide launches (r14).
  k_init<<<2048, 256, 0, stream>>>(P);
  k_mean2<<<32, 256, 0, stream>>>(P);
  k_qkvsp<<<848, 256, 0, stream>>>(P);
  k_sat<<<MM/4, 256, 0, stream>>>(P, P.qbuf, 512, P.KeVe, P.KeVe + 512, 1024);
  k_gemm<<<256, 256, 0, stream>>>(P, P.ctxbf, P.WtO,
      P.sat_ob, P.sat_ob, P.sat_ob, P.sat_ob, P.sat_ob, aout, 512, aout, 512, 512);
  k_ln<<<MM/4, 256, 0, stream>>>(P, aout, hbf);
  k_gemm<<<1280, 256, 0, stream>>>(P, hbf, P.WtAll,
      P.sat_qb, P.sat_kb, P.sat_vb, P.rel_kb, P.rel_vb, P.qkv, 1536, P.kvbuf, 1024, 1536);
  k_relp<<<BB*NHH*RCH, 256, 0, stream>>>(P);
  k_reltail2<<<256, 256, 0, stream>>>(P);
  k_lnrel<<<4, 256, 0, stream>>>(P);
  k_sproj<<<32, 256, 0, stream>>>(P);
  k_sat<<<MM/4, 256, 0, stream>>>(P, P.qkv, 1536, P.qkv + 512, P.qkv + 1024, 1536);
  k_gemm<<<256, 256, 0, stream>>>(P, P.ctxbf, P.WtO,
      P.sat_ob, P.sat_ob, P.sat_ob, P.sat_ob, P.sat_ob, aout, 512, aout, 512, 512);
  k_ln<<<MM/4, 256, 0, stream>>>(P, aout, hbf);
  k_logits<<<64, 256, 0, stream>>>(P);
}

// Round 17
// 310.933 us; speedup vs baseline: 1.1564x; 1.1564x over previous
//
#include <hip/hip_runtime.h>
#include <hip/hip_bf16.h>

typedef __hip_bfloat16 bf16;

#define BB 16
#define LL 512
#define DD 512
#define NHH 8
#define HDD 64
#define TT 17
#define MM (BB*LL)
#define RCH 8
#define RCK 65

typedef __attribute__((ext_vector_type(8))) short bfrag;
typedef __attribute__((ext_vector_type(4))) float ffrag;
typedef __attribute__((ext_vector_type(8))) unsigned short us8;

struct Params {
  const int* tokens;
  const float* emb;
  const float *sat_qw, *sat_qb, *sat_kw, *sat_kb, *sat_vw, *sat_vb, *sat_ow, *sat_ob;
  const float *rel_qw, *rel_qb, *rel_kw, *rel_kb, *rel_vw, *rel_vb, *rel_ow, *rel_ob;
  const float *ln_sat_w, *ln_sat_b, *ln_rel_w, *ln_rel_b, *ofc_w, *ofc_b;
  bf16 *ebf, *qkv, *kvbuf, *KeVe, *qbuf, *ctxbf, *WtAll, *WtO, *WtLog;
  float *s, *KsVs, *qr, *Ksr, *Vsr, *mpart, *pws, *out;
};

static __device__ __forceinline__ void gld16(const void* g, void* l){
  __builtin_amdgcn_global_load_lds((const __attribute__((address_space(1))) void*)g,
                                   (__attribute__((address_space(3))) void*)l, 16, 0, 0);
}
static __device__ __forceinline__ float us2f(unsigned short u){
  unsigned int v = ((unsigned int)u) << 16;
  float f; __builtin_memcpy(&f, &v, 4); return f;
}
static __device__ __forceinline__ float hsum8(float v){
  v += __shfl_xor(v, 1); v += __shfl_xor(v, 2); v += __shfl_xor(v, 4);
  return v;
}

// ---------------- init: embed+mean partials (u<256) | weight prep ----------------
__global__ __launch_bounds__(256) void k_init(Params P){
  __shared__ __align__(16) char sm[8192];
  int u = blockIdx.x, t = threadIdx.x;
  if (u < 256){
    int* toks = (int*)sm;
    int b = u >> 4, lc = u & 15;
    if (t < 32) toks[t] = P.tokens[b*LL + lc*32 + t];
    __syncthreads();
    bf16* eb = P.ebf + ((size_t)b*LL + lc*32)*DD;
    for (int d = t; d < DD; d += 256){
      float acc = 0.f;
      #pragma unroll 4
      for (int l = 0; l < 32; l++){
        float v = P.emb[(size_t)toks[l]*DD + d];
        eb[(size_t)l*DD + d] = __float2bfloat16(v);
        acc += v;
      }
      P.mpart[(size_t)u*DD + d] = acc;
    }
    return;
  }
  int w = u - 256;
  int z = w >> 8, xy = w & 255;
  int tx = t & 31, ty = t >> 5;
  if (z == 6){
    int i = (xy << 8) + t;
    int row = i >> 9, k = i & 511;
    P.WtLog[i] = __float2bfloat16(row < TT ? P.ofc_w[(size_t)k*TT + row] : 0.f);
    return;
  }
  float (*tile)[33] = (float(*)[33])sm;
  const float* in = (z==0)?P.sat_qw:(z==1)?P.sat_kw:(z==2)?P.sat_vw:
                    (z==3)?P.rel_kw:(z==4)?P.rel_vw:P.sat_ow;
  bf16* out = (z<5) ? (P.WtAll + (size_t)z*512*512) : P.WtO;
  int bx = (xy & 15)*32, by = (xy >> 4)*32;
  #pragma unroll
  for (int j = 0; j < 32; j += 8)
    tile[ty + j][tx] = in[(size_t)(by + ty + j)*DD + bx + tx];
  __syncthreads();
  #pragma unroll
  for (int j = 0; j < 32; j += 8)
    out[(size_t)(bx + ty + j)*DD + by + tx] = __float2bfloat16(tile[tx][ty + j]);
}

// ---------------- mean stage 2: s[16,512] ----------------
__global__ __launch_bounds__(256) void k_mean2(Params P){
  int i = blockIdx.x*256 + threadIdx.x;   // 8192
  int b = i >> 9, d = i & 511;
  float acc = 0.f;
  #pragma unroll
  for (int c = 0; c < 16; c++) acc += P.mpart[(size_t)(b*16 + c)*DD + d];
  P.s[i] = acc * (1.0f/LL);
}

// ---------------- batched s-projections: 8-way split-k, 32-col chunks ----------------
__global__ __launch_bounds__(256)
void k_sproj(Params P,
             const float* W0, const float* W1, const float* W2, const float* W3,
             const float* W4,
             const float* bias0, const float* bias1, const float* bias2,
             const float* bias3, const float* bias4,
             float* O0, float* O1, float* O2, float* O3, float* O4,
             int ldc0, int ldc1, int ldc2, int ldc3, int ldc4){
  __shared__ float part[8][32][17];
  const float* A = P.s;
  int t = threadIdx.x;
  int n = t & 31, kg = t >> 5;
  int wi = blockIdx.x >> 4, ch = blockIdx.x & 15;
  const float* W  = (wi==0)?W0:(wi==1)?W1:(wi==2)?W2:(wi==3)?W3:W4;
  const float* bs = (wi==0)?bias0:(wi==1)?bias1:(wi==2)?bias2:(wi==3)?bias3:bias4;
  float* O  = (wi==0)?O0:(wi==1)?O1:(wi==2)?O2:(wi==3)?O3:O4;
  int ldc   = (wi==0)?ldc0:(wi==1)?ldc1:(wi==2)?ldc2:(wi==3)?ldc3:ldc4;
  int col = ch*32 + n;
  float acc[16];
  #pragma unroll
  for (int m = 0; m < 16; m++) acc[m] = 0.f;
  const float* Wp = W + (size_t)(kg*64)*512 + col;
  const float* Ap = A + kg*64;
  for (int k = 0; k < 64; k++){
    float w = Wp[(size_t)k*512];
    #pragma unroll
    for (int m = 0; m < 16; m++) acc[m] = fmaf(Ap[m*512 + k], w, acc[m]);
  }
  #pragma unroll
  for (int m = 0; m < 16; m++) part[kg][n][m] = acc[m];
  __syncthreads();
  for (int o = t; o < 512; o += 256){
    int m = o >> 5, nn = o & 31;
    float v = 0.f;
    #pragma unroll
    for (int g = 0; g < 8; g++) v += part[g][nn][m];
    O[(size_t)m*ldc + ch*32 + nn] = v + bs[ch*32 + nn];
  }
}

// ---------------- MFMA GEMM (standalone body — r16 lesson: device-fn refactor
// doubled VGPR 80->164 and halved occupancy; keep inlined) ----------------
__global__ __launch_bounds__(256)
void k_gemm(Params P, const bf16* __restrict__ A, const bf16* __restrict__ Wt,
            const float* b0, const float* b1, const float* b2, const float* b3,
            const float* b4,
            bf16* D0, int ld0, bf16* D1, int ld1, int split){
  const int K = 512;
  __shared__ bf16 As[128*32];
  __shared__ bf16 Bs[128*32];
  int t = threadIdx.x;
  int wave = t >> 6, lane = t & 63;
  int id = blockIdx.x;
  int bm = (((id & 7) << 3) | ((id >> 3) & 7)) * 128;
  int bn = (id >> 6) * 128;
  int wm = (wave & 1) * 64, wn = (wave >> 1) * 64;
  ffrag acc[4][4];
  #pragma unroll
  for (int i = 0; i < 4; i++)
    #pragma unroll
    for (int j = 0; j < 4; j++) acc[i][j] = (ffrag){0.f,0.f,0.f,0.f};

  int srow = t >> 2;
  // bank-conflict-free swizzle (r13/r15: SQ_LDS_BANK_CONFLICT = 0, verified)
  int scol = ((((t & 3) - ((t >> 3) & 3)) & 3)) * 8;
  const bf16* gA = A  + (size_t)(bm + srow)*K + scol;
  const bf16* gB = Wt + (size_t)(bn + srow)*K + scol;
  char* lA = (char*)As + 16*t;
  char* lB = (char*)Bs + 16*t;
  int q = lane >> 4, r = lane & 15;
  int cs = (((q + (r >> 1)) & 3)) * 8;

  for (int k0 = 0; k0 < K; k0 += 32){
    gld16(gA + k0,          lA);
    gld16(gA + 64*K + k0,   lA + 4096);
    gld16(gB + k0,          lB);
    gld16(gB + 64*K + k0,   lB + 4096);
    __syncthreads();
    bfrag af[4], bfv[4];
    #pragma unroll
    for (int i = 0; i < 4; i++){
      af[i]  = *(const bfrag*)(As + (wm + i*16 + r)*32 + cs);
      bfv[i] = *(const bfrag*)(Bs + (wn + i*16 + r)*32 + cs);
    }
    #pragma unroll
    for (int i = 0; i < 4; i++)
      #pragma unroll
      for (int j = 0; j < 4; j++)
        acc[i][j] = __builtin_amdgcn_mfma_f32_16x16x32_bf16(af[i], bfv[j], acc[i][j], 0, 0, 0);
    __syncthreads();
  }
  #pragma unroll
  for (int i = 0; i < 4; i++){
    #pragma unroll
    for (int j = 0; j < 4; j++){
      int row = bm + wm + i*16 + q*4;
      int col = bn + wn + j*16 + r;
      const float* bp = (col < 512) ? b0 : (col < 1024) ? b1 :
                        (col < 1536) ? b2 : (col < 2048) ? b3 : b4;
      float bias = bp[col & 511];
      bf16* D; int ld;
      if (col < split){ D = D0 + (size_t)row*ld0 + col;         ld = ld0; }
      else            { D = D1 + (size_t)row*ld1 + (col-split); ld = ld1; }
      #pragma unroll
      for (int g = 0; g < 4; g++)
        D[(size_t)g*ld] = __float2bfloat16(acc[i][j][g] + bias);
    }
  }
}

// ---------------- logits GEMM: masked to cols<32 (17 used) ----------------
__global__ __launch_bounds__(256) void k_logits(Params P){
  const int K = 512;
  __shared__ bf16 As[128*32];
  __shared__ bf16 Bs[128*32];
  int t = threadIdx.x;
  int wave = t >> 6, lane = t & 63;
  int bm = blockIdx.x * 128;
  int wm = (wave & 1) * 64, wn = (wave >> 1) * 64;
  ffrag acc[4][2];
  #pragma unroll
  for (int i = 0; i < 4; i++){ acc[i][0] = (ffrag){0,0,0,0}; acc[i][1] = (ffrag){0,0,0,0}; }
  int srow = t >> 2;
  int scol = ((((t & 3) - ((t >> 3) & 3)) & 3)) * 8;
  const bf16* gA = P.ebf + (size_t)(bm + srow)*K + scol;   // hbf aliases ebf
  const bf16* gB = P.WtLog + (size_t)srow*K + scol;
  char* lA = (char*)As + 16*t;
  char* lB = (char*)Bs + 16*t;
  int q = lane >> 4, r = lane & 15;
  int cs = (((q + (r >> 1)) & 3)) * 8;

  for (int k0 = 0; k0 < K; k0 += 32){
    gld16(gA + k0,          lA);
    gld16(gA + 64*K + k0,   lA + 4096);
    gld16(gB + k0,          lB);
    gld16(gB + 64*K + k0,   lB + 4096);
    __syncthreads();
    if (wn == 0){
      bfrag bf0 = *(const bfrag*)(Bs + (r)*32 + cs);
      bfrag bf1 = *(const bfrag*)(Bs + (16 + r)*32 + cs);
      #pragma unroll
      for (int i = 0; i < 4; i++){
        bfrag af = *(const bfrag*)(As + (wm + i*16 + r)*32 + cs);
        acc[i][0] = __builtin_amdgcn_mfma_f32_16x16x32_bf16(af, bf0, acc[i][0], 0, 0, 0);
        acc[i][1] = __builtin_amdgcn_mfma_f32_16x16x32_bf16(af, bf1, acc[i][1], 0, 0, 0);
      }
    }
    __syncthreads();
  }
  if (wn == 0){
    #pragma unroll
    for (int i = 0; i < 4; i++)
      #pragma unroll
      for (int j = 0; j < 2; j++){
        int row = bm + wm + i*16 + q*4;
        int col = j*16 + r;
        if (col < TT){
          float bv = P.ofc_b[col];
          #pragma unroll
          for (int g = 0; g < 4; g++)
            P.out[(size_t)(row + g)*TT + col] = acc[i][j][g] + bv;
        }
      }
  }
}

// ---------------- sat attention: wave/token, us8 loads ----------------
__global__ __launch_bounds__(256)
void k_sat(Params P, const bf16* qp, int sq, const bf16* kp, const bf16* vp, int skv){
  int tok = blockIdx.x*4 + (threadIdx.x >> 6);
  int l = threadIdx.x & 63;
  int b = tok >> 9, li = tok & 511;
  int off = l*8;
  int t0 = (b << 9) | ((li + 1) & 511);
  int t2 = (b << 9) | (li == 0 ? 511 : 0);
  float qf[8];
  { us8 q8 = *(const us8*)(qp + (size_t)tok*sq + off);
    #pragma unroll
    for (int g = 0; g < 8; g++) qf[g] = us2f(q8[g]); }
  float sc[5];
  int rows[3] = {t0, tok, t2};
  #pragma unroll
  for (int j = 0; j < 3; j++){
    us8 k8 = *(const us8*)(kp + (size_t)rows[j]*skv + off);
    float a = 0.f;
    #pragma unroll
    for (int g = 0; g < 8; g++) a += qf[g]*us2f(k8[g]);
    sc[j] = hsum8(a) * 0.125f;
  }
  { us8 k8 = *(const us8*)(P.KeVe + (size_t)tok*1024 + off);
    float a = 0.f;
    #pragma unroll
    for (int g = 0; g < 8; g++) a += qf[g]*us2f(k8[g]);
    sc[3] = hsum8(a) * 0.125f; }
  { const float* ks = P.KsVs + (size_t)b*1024 + off;
    float4 f0 = *(const float4*)ks, f1 = *(const float4*)(ks + 4);
    float a = qf[0]*f0.x + qf[1]*f0.y + qf[2]*f0.z + qf[3]*f0.w
            + qf[4]*f1.x + qf[5]*f1.y + qf[6]*f1.z + qf[7]*f1.w;
    sc[4] = hsum8(a) * 0.125f; }
  float m = fmaxf(fmaxf(fmaxf(sc[0],sc[1]), fmaxf(sc[2],sc[3])), sc[4]);
  float pr[5], den = 0.f;
  #pragma unroll
  for (int j = 0; j < 5; j++){ pr[j] = __expf(sc[j]-m); den += pr[j]; }
  float inv = 1.0f/den;
  float o[8];
  #pragma unroll
  for (int g = 0; g < 8; g++) o[g] = 0.f;
  #pragma unroll
  for (int j = 0; j < 3; j++){
    us8 v8 = *(const us8*)(vp + (size_t)rows[j]*skv + off);
    #pragma unroll
    for (int g = 0; g < 8; g++) o[g] += pr[j]*us2f(v8[g]);
  }
  { us8 v8 = *(const us8*)(P.KeVe + (size_t)tok*1024 + 512 + off);
    #pragma unroll
    for (int g = 0; g < 8; g++) o[g] += pr[3]*us2f(v8[g]); }
  { const float* vs = P.KsVs + (size_t)b*1024 + 512 + off;
    float4 f0 = *(const float4*)vs, f1 = *(const float4*)(vs + 4);
    o[0] += pr[4]*f0.x; o[1] += pr[4]*f0.y; o[2] += pr[4]*f0.z; o[3] += pr[4]*f0.w;
    o[4] += pr[4]*f1.x; o[5] += pr[4]*f1.y; o[6] += pr[4]*f1.z; o[7] += pr[4]*f1.w; }
  bf16 ob[8];
  #pragma unroll
  for (int g = 0; g < 8; g++) ob[g] = __float2bfloat16(o[g]*inv);
  *(us8*)(P.ctxbf + (size_t)tok*DD + off) = *(const us8*)ob;
}

// ---------------- wave-per-row relu+LN (sat), bf16 ----------------
__global__ __launch_bounds__(256) void k_ln(Params P, const bf16* X, bf16* Y){
  int row = blockIdx.x*4 + (threadIdx.x >> 6);
  int lane = threadIdx.x & 63;
  int off = lane*8;
  us8 x8 = *(const us8*)(X + (size_t)row*DD + off);
  float v[8], sum = 0.f;
  #pragma unroll
  for (int g = 0; g < 8; g++){ v[g] = fmaxf(us2f(x8[g]), 0.f); sum += v[g]; }
  #pragma unroll
  for (int o = 32; o; o >>= 1) sum += __shfl_xor(sum, o);
  float u = sum * (1.0f/DD);
  float d[8], var = 0.f;
  #pragma unroll
  for (int g = 0; g < 8; g++){ d[g] = v[g] - u; var += d[g]*d[g]; }
  #pragma unroll
  for (int o = 32; o; o >>= 1) var += __shfl_xor(var, o);
  float inv = rsqrtf(var * (1.0f/DD) + 1e-12f);
  bf16 ob[8];
  #pragma unroll
  for (int g = 0; g < 8; g++)
    ob[g] = __float2bfloat16(P.ln_sat_w[off+g]*d[g]*inv + P.ln_sat_b[off+g]);
  *(us8*)(Y + (size_t)row*DD + off) = *(const us8*)ob;
}

// ---------------- rel attention partials ----------------
__global__ __launch_bounds__(256) void k_relp(Params P){
  __shared__ __align__(16) char sm[4096];
  int u = blockIdx.x, t = threadIdx.x;
  int ch = u & 7, hh = (u >> 3) & 7, b = u >> 6;
  float* qs   = (float*)sm;
  float* sc   = (float*)(sm + 256);
  float* red  = (float*)(sm + 1024);
  float (*part)[64] = (float(*)[64])(sm + 2048);
  int base = hh * HDD;
  int j0 = ch * RCK;
  int nk = min(513 - j0, RCK);
  if (t < 64) qs[t] = P.qr[(size_t)b*DD + base + t];
  __syncthreads();
  if (t < nk){
    int j = j0 + t;
    float a = 0.f;
    if (j == 0){
      const float* kr = P.Ksr + (size_t)b*DD + base;
      #pragma unroll
      for (int d = 0; d < 64; d += 4){
        float4 k4 = *(const float4*)(kr + d);
        float4 q4 = *(const float4*)(qs + d);
        a += q4.x*k4.x + q4.y*k4.y + q4.z*k4.z + q4.w*k4.w;
      }
    } else {
      const bf16* kr = P.kvbuf + ((size_t)b*LL + j - 1)*1024 + base;
      #pragma unroll
      for (int d = 0; d < 64; d += 8){
        us8 k8 = *(const us8*)(kr + d);
        #pragma unroll
        for (int g = 0; g < 8; g++) a += qs[d+g] * us2f(k8[g]);
      }
    }
    sc[t] = a * 0.125f;
  }
  __syncthreads();
  red[t] = (t < nk) ? sc[t] : -1e30f; __syncthreads();
  for (int st = 128; st; st >>= 1){ if (t < st) red[t] = fmaxf(red[t], red[t+st]); __syncthreads(); }
  float m = red[0]; __syncthreads();
  if (t < nk) sc[t] = __expf(sc[t] - m);
  __syncthreads();
  red[t] = (t < nk) ? sc[t] : 0.f; __syncthreads();
  for (int st = 128; st; st >>= 1){ if (t < st) red[t] += red[t+st]; __syncthreads(); }
  float l = red[0];
  int d = t & 63, c2 = t >> 6;
  float a = 0.f;
  for (int j = c2; j < nk; j += 4){
    int gj = j0 + j;
    float vv = (gj == 0) ? P.Vsr[(size_t)b*DD + base + d]
                         : __bfloat162float(P.kvbuf[((size_t)b*LL + gj - 1)*1024 + 512 + base + d]);
    a += sc[j] * vv;
  }
  part[c2][d] = a; __syncthreads();
  float* o = P.pws + (((size_t)(b*NHH + hh))*RCH + ch) * 66;
  if (t < 64) o[t] = part[0][t] + part[1][t] + part[2][t] + part[3][t];
  else if (t == 64) o[64] = m;
  else if (t == 65) o[65] = l;
}

// ---------------- rel tail pass A: combine + split-k out-proj (256 blocks) ----------------
// block = (b, 32-col chunk); writes rr (= reuse of qr, dead after k_relp)
__global__ __launch_bounds__(256) void k_reltail2(Params P){
  __shared__ float crs[512];
  __shared__ float part[8][33];
  int b = blockIdx.x >> 4, ch = blockIdx.x & 15;
  int t = threadIdx.x;
  for (int o = t; o < 512; o += 256){
    int hh = o >> 6, d = o & 63;
    const float* p = P.pws + ((size_t)(b*NHH + hh))*RCH*66;
    float M = -1e30f;
    #pragma unroll
    for (int c = 0; c < RCH; c++) M = fmaxf(M, p[c*66 + 64]);
    float den = 0.f, acc = 0.f;
    #pragma unroll
    for (int c = 0; c < RCH; c++){
      float w = __expf(p[c*66 + 64] - M);
      den += w * p[c*66 + 65];
      acc += w * p[c*66 + d];
    }
    crs[o] = acc / den;
  }
  __syncthreads();
  int n = t & 31, kg = t >> 5;
  int col = ch*32 + n;
  const float* Wp = P.rel_ow + (size_t)(kg*64)*512 + col;
  const float* cp = crs + kg*64;
  float a = 0.f;
  for (int k = 0; k < 64; k++) a = fmaf(cp[k], Wp[(size_t)k*512], a);
  part[kg][n] = a;
  __syncthreads();
  if (t < 32){
    float v = P.rel_ob[ch*32 + t];
    #pragma unroll
    for (int g = 0; g < 8; g++) v += part[g][t];
    P.qr[(size_t)b*DD + ch*32 + t] = v;   // rr aliases qr
  }
}

// ---------------- rel tail pass B: relu+LN (fp32, wave-per-row) -> s ----------------
__global__ __launch_bounds__(256) void k_lnrel(Params P){
  int row = blockIdx.x*4 + (threadIdx.x >> 6);   // 4 blocks x 4 rows
  int lane = threadIdx.x & 63;
  int off = lane*8;
  const float* x = P.qr + (size_t)row*DD + off;
  float4 f0 = *(const float4*)x, f1 = *(const float4*)(x + 4);
  float v[8] = {f0.x, f0.y, f0.z, f0.w, f1.x, f1.y, f1.z, f1.w};
  float sum = 0.f;
  #pragma unroll
  for (int g = 0; g < 8; g++){ v[g] = fmaxf(v[g], 0.f); sum += v[g]; }
  #pragma unroll
  for (int o = 32; o; o >>= 1) sum += __shfl_xor(sum, o);
  float u = sum * (1.0f/DD);
  float d[8], var = 0.f;
  #pragma unroll
  for (int g = 0; g < 8; g++){ d[g] = v[g] - u; var += d[g]*d[g]; }
  #pragma unroll
  for (int o = 32; o; o >>= 1) var += __shfl_xor(var, o);
  float inv = rsqrtf(var * (1.0f/DD) + 1e-12f);
  // s MUST be written — feeds the c1 KsVs projection (round-5 lesson).
  #pragma unroll
  for (int g = 0; g < 8; g++)
    P.s[(size_t)row*DD + off + g] = P.ln_rel_w[off+g]*d[g]*inv + P.ln_rel_b[off+g];
}

extern "C" void kernel_launch(void* const* d_in, const int* in_sizes, int n_in,
                              void* d_out, int out_size, void* d_ws, size_t ws_size,
                              hipStream_t stream) {
  Params P;
  P.tokens  = (const int*)  d_in[0];
  P.emb     = (const float*)d_in[4];
  P.sat_qw  = (const float*)d_in[5];  P.sat_qb = (const float*)d_in[6];
  P.sat_kw  = (const float*)d_in[7];  P.sat_kb = (const float*)d_in[8];
  P.sat_vw  = (const float*)d_in[9];  P.sat_vb = (const float*)d_in[10];
  P.sat_ow  = (const float*)d_in[11]; P.sat_ob = (const float*)d_in[12];
  P.rel_qw  = (const float*)d_in[13]; P.rel_qb = (const float*)d_in[14];
  P.rel_kw  = (const float*)d_in[15]; P.rel_kb = (const float*)d_in[16];
  P.rel_vw  = (const float*)d_in[17]; P.rel_vb = (const float*)d_in[18];
  P.rel_ow  = (const float*)d_in[19]; P.rel_ob = (const float*)d_in[20];
  P.ln_sat_w= (const float*)d_in[21]; P.ln_sat_b= (const float*)d_in[22];
  P.ln_rel_w= (const float*)d_in[23]; P.ln_rel_b= (const float*)d_in[24];
  P.ofc_w   = (const float*)d_in[25]; P.ofc_b  = (const float*)d_in[26];

  char* p = (char*)d_ws;
  auto alloc = [&](size_t bytes) -> char* {
    char* r = p; p += (bytes + 255) & ~(size_t)255; return r;
  };
  const size_t BIGH = (size_t)MM*DD*2;
  P.ebf   = (bf16*) alloc(BIGH);
  P.qkv   = (bf16*) alloc(3*BIGH);
  P.kvbuf = (bf16*) alloc(2*BIGH);
  P.KeVe  = (bf16*) alloc(2*BIGH);
  P.qbuf  = (bf16*) alloc(BIGH);
  P.ctxbf = (bf16*) alloc(BIGH);
  P.WtAll = (bf16*) alloc((size_t)2560*512*2);
  P.WtO   = (bf16*) alloc((size_t)512*512*2);
  P.WtLog = (bf16*) alloc((size_t)128*512*2);
  P.s     = (float*)alloc(BB*DD*4);
  P.KsVs  = (float*)alloc(BB*1024*4);
  P.qr    = (float*)alloc(BB*DD*4);
  P.Ksr   = (float*)alloc(BB*DD*4);
  P.Vsr   = (float*)alloc(BB*DD*4);
  P.mpart = (float*)alloc((size_t)256*DD*4);
  P.pws   = (float*)alloc((size_t)BB*NHH*RCH*66*4);
  P.out   = (float*)d_out;

  bf16* hbf  = P.ebf;   // h aliases e
  bf16* aout = P.qkv;   // out-proj scratch aliases qkv

  // 16 launches; no grid.sync (r13); no long-serial blocks (r14);
  // GEMM bodies standalone (r16 VGPR lesson).
  k_init<<<2048, 256, 0, stream>>>(P);
  k_mean2<<<32, 256, 0, stream>>>(P);
  k_sproj<<<80, 256, 0, stream>>>(P,
      P.sat_kw, P.sat_vw, P.rel_qw, P.rel_kw, P.rel_vw,
      P.sat_kb, P.sat_vb, P.rel_qb, P.rel_kb, P.rel_vb,
      P.KsVs, P.KsVs + 512, P.qr, P.Ksr, P.Vsr,
      1024, 1024, 512, 512, 512);
  k_gemm<<<768, 256, 0, stream>>>(P, P.ebf, P.WtAll,
      P.sat_qb, P.sat_kb, P.sat_vb, P.sat_vb, P.sat_vb, P.qbuf, 512, P.KeVe, 1024, 512);
  k_sat<<<MM/4, 256, 0, stream>>>(P, P.qbuf, 512, P.KeVe, P.KeVe + 512, 1024);
  k_gemm<<<256, 256, 0, stream>>>(P, P.ctxbf, P.WtO,
      P.sat_ob, P.sat_ob, P.sat_ob, P.sat_ob, P.sat_ob, aout, 512, aout, 512, 512);
  k_ln<<<MM/4, 256, 0, stream>>>(P, aout, hbf);
  k_gemm<<<1280, 256, 0, stream>>>(P, hbf, P.WtAll,
      P.sat_qb, P.sat_kb, P.sat_vb, P.rel_kb, P.rel_vb, P.qkv, 1536, P.kvbuf, 1024, 1536);
  k_relp<<<BB*NHH*RCH, 256, 0, stream>>>(P);
  k_reltail2<<<256, 256, 0, stream>>>(P);
  k_lnrel<<<4, 256, 0, stream>>>(P);
  k_sproj<<<32, 256, 0, stream>>>(P,
      P.sat_kw, P.sat_vw, P.sat_vw, P.sat_vw, P.sat_vw,
      P.sat_kb, P.sat_vb, P.sat_vb, P.sat_vb, P.sat_vb,
      P.KsVs, P.KsVs + 512, P.Vsr, P.Vsr, P.Vsr,
      1024, 1024, 512, 512, 512);
  k_sat<<<MM/4, 256, 0, stream>>>(P, P.qkv, 1536, P.qkv + 512, P.qkv + 1024, 1536);
  k_gemm<<<256, 256, 0, stream>>>(P, P.ctxbf, P.WtO,
      P.sat_ob, P.sat_ob, P.sat_ob, P.sat_ob, P.sat_ob, aout, 512, aout, 512, 512);
  k_ln<<<MM/4, 256, 0, stream>>>(P, aout, hbf);
  k_logits<<<64, 256, 0, stream>>>(P);
}

// Round 18
// 305.187 us; speedup vs baseline: 1.1782x; 1.0188x over previous
//
#include <hip/hip_runtime.h>
#include <hip/hip_bf16.h>

typedef __hip_bfloat16 bf16;

#define BB 16
#define LL 512
#define DD 512
#define NHH 8
#define HDD 64
#define TT 17
#define MM (BB*LL)
#define RCH 8
#define RCK 65

typedef __attribute__((ext_vector_type(8))) short bfrag;
typedef __attribute__((ext_vector_type(4))) float ffrag;
typedef __attribute__((ext_vector_type(8))) unsigned short us8;

struct Params {
  const int* tokens;
  const float* emb;
  const float *sat_qw, *sat_qb, *sat_kw, *sat_kb, *sat_vw, *sat_vb, *sat_ow, *sat_ob;
  const float *rel_qw, *rel_qb, *rel_kw, *rel_kb, *rel_vw, *rel_vb, *rel_ow, *rel_ob;
  const float *ln_sat_w, *ln_sat_b, *ln_rel_w, *ln_rel_b, *ofc_w, *ofc_b;
  bf16 *ebf, *qkv, *kvbuf, *KeVe, *qbuf, *ctxbf, *WtAll, *WtO, *WtLog;
  float *s, *KsVs, *qr, *Ksr, *Vsr, *mpart, *pws, *out;
};

static __device__ __forceinline__ void gld16(const void* g, void* l){
  __builtin_amdgcn_global_load_lds((const __attribute__((address_space(1))) void*)g,
                                   (__attribute__((address_space(3))) void*)l, 16, 0, 0);
}
static __device__ __forceinline__ float us2f(unsigned short u){
  unsigned int v = ((unsigned int)u) << 16;
  float f; __builtin_memcpy(&f, &v, 4); return f;
}
static __device__ __forceinline__ float hsum8(float v){
  v += __shfl_xor(v, 1); v += __shfl_xor(v, 2); v += __shfl_xor(v, 4);
  return v;
}

// ---------------- init: embed+mean partials (u<256) | weight prep ----------------
__global__ __launch_bounds__(256) void k_init(Params P){
  __shared__ __align__(16) char sm[8192];
  int u = blockIdx.x, t = threadIdx.x;
  if (u < 256){
    int* toks = (int*)sm;
    int b = u >> 4, lc = u & 15;
    if (t < 32) toks[t] = P.tokens[b*LL + lc*32 + t];
    __syncthreads();
    bf16* eb = P.ebf + ((size_t)b*LL + lc*32)*DD;
    for (int d = t; d < DD; d += 256){
      float acc = 0.f;
      #pragma unroll 4
      for (int l = 0; l < 32; l++){
        float v = P.emb[(size_t)toks[l]*DD + d];
        eb[(size_t)l*DD + d] = __float2bfloat16(v);
        acc += v;
      }
      P.mpart[(size_t)u*DD + d] = acc;
    }
    return;
  }
  int w = u - 256;
  int z = w >> 8, xy = w & 255;
  int tx = t & 31, ty = t >> 5;
  if (z == 6){
    int i = (xy << 8) + t;
    int row = i >> 9, k = i & 511;
    P.WtLog[i] = __float2bfloat16(row < TT ? P.ofc_w[(size_t)k*TT + row] : 0.f);
    return;
  }
  float (*tile)[33] = (float(*)[33])sm;
  const float* in = (z==0)?P.sat_qw:(z==1)?P.sat_kw:(z==2)?P.sat_vw:
                    (z==3)?P.rel_kw:(z==4)?P.rel_vw:P.sat_ow;
  bf16* out = (z<5) ? (P.WtAll + (size_t)z*512*512) : P.WtO;
  int bx = (xy & 15)*32, by = (xy >> 4)*32;
  #pragma unroll
  for (int j = 0; j < 32; j += 8)
    tile[ty + j][tx] = in[(size_t)(by + ty + j)*DD + bx + tx];
  __syncthreads();
  #pragma unroll
  for (int j = 0; j < 32; j += 8)
    out[(size_t)(bx + ty + j)*DD + by + tx] = __float2bfloat16(tile[tx][ty + j]);
}

// ---------------- c0 s-projections with fused mean (s built in LDS from mpart) ----------------
__global__ __launch_bounds__(256)
void k_sproj0(Params P){
  __shared__ float sL[16][512];        // 32 KB
  __shared__ float part[8][32][17];    // 17.4 KB
  int t = threadIdx.x;
  // build s[16][512] from mpart (mpart is L2-resident; redundancy is cheap)
  for (int o = t; o < 8192; o += 256){
    int m = o >> 9, d = o & 511;
    float a = 0.f;
    #pragma unroll
    for (int c = 0; c < 16; c++) a += P.mpart[(size_t)(m*16 + c)*DD + d];
    sL[m][d] = a * (1.0f/LL);
  }
  __syncthreads();
  int n = t & 31, kg = t >> 5;
  int wi = blockIdx.x >> 4, ch = blockIdx.x & 15;
  const float* W  = (wi==0)?P.sat_kw:(wi==1)?P.sat_vw:(wi==2)?P.rel_qw:
                    (wi==3)?P.rel_kw:P.rel_vw;
  const float* bs = (wi==0)?P.sat_kb:(wi==1)?P.sat_vb:(wi==2)?P.rel_qb:
                    (wi==3)?P.rel_kb:P.rel_vb;
  float* O  = (wi==0)?P.KsVs:(wi==1)?(P.KsVs+512):(wi==2)?P.qr:(wi==3)?P.Ksr:P.Vsr;
  int ldc   = (wi<2) ? 1024 : 512;
  int col = ch*32 + n;
  float acc[16];
  #pragma unroll
  for (int m = 0; m < 16; m++) acc[m] = 0.f;
  const float* Wp = W + (size_t)(kg*64)*512 + col;
  for (int k = 0; k < 64; k++){
    float w = Wp[(size_t)k*512];
    int kk = kg*64 + k;
    #pragma unroll
    for (int m = 0; m < 16; m++) acc[m] = fmaf(sL[m][kk], w, acc[m]);
  }
  #pragma unroll
  for (int m = 0; m < 16; m++) part[kg][n][m] = acc[m];
  __syncthreads();
  for (int o = t; o < 512; o += 256){
    int m = o >> 5, nn = o & 31;
    float v = 0.f;
    #pragma unroll
    for (int g = 0; g < 8; g++) v += part[g][nn][m];
    O[(size_t)m*ldc + ch*32 + nn] = v + bs[ch*32 + nn];
  }
}

// ---------------- c1 s-projections (A = P.s, written by k_lnrel) ----------------
__global__ __launch_bounds__(256)
void k_sproj1(Params P){
  __shared__ float part[8][32][17];
  int t = threadIdx.x;
  int n = t & 31, kg = t >> 5;
  int wi = blockIdx.x >> 4, ch = blockIdx.x & 15;   // wi in 0..1
  const float* W  = (wi==0)?P.sat_kw:P.sat_vw;
  const float* bs = (wi==0)?P.sat_kb:P.sat_vb;
  float* O  = (wi==0)?P.KsVs:(P.KsVs+512);
  int col = ch*32 + n;
  float acc[16];
  #pragma unroll
  for (int m = 0; m < 16; m++) acc[m] = 0.f;
  const float* Wp = W + (size_t)(kg*64)*512 + col;
  const float* Ap = P.s + kg*64;
  for (int k = 0; k < 64; k++){
    float w = Wp[(size_t)k*512];
    #pragma unroll
    for (int m = 0; m < 16; m++) acc[m] = fmaf(Ap[m*512 + k], w, acc[m]);
  }
  #pragma unroll
  for (int m = 0; m < 16; m++) part[kg][n][m] = acc[m];
  __syncthreads();
  for (int o = t; o < 512; o += 256){
    int m = o >> 5, nn = o & 31;
    float v = 0.f;
    #pragma unroll
    for (int g = 0; g < 8; g++) v += part[g][nn][m];
    O[(size_t)m*1024 + ch*32 + nn] = v + bs[ch*32 + nn];
  }
}

// ---------------- MFMA GEMM (standalone body — r16 VGPR lesson) ----------------
__global__ __launch_bounds__(256)
void k_gemm(Params P, const bf16* __restrict__ A, const bf16* __restrict__ Wt,
            const float* b0, const float* b1, const float* b2, const float* b3,
            const float* b4,
            bf16* D0, int ld0, bf16* D1, int ld1, int split){
  const int K = 512;
  __shared__ bf16 As[128*32];
  __shared__ bf16 Bs[128*32];
  int t = threadIdx.x;
  int wave = t >> 6, lane = t & 63;
  int id = blockIdx.x;
  int bm = (((id & 7) << 3) | ((id >> 3) & 7)) * 128;
  int bn = (id >> 6) * 128;
  int wm = (wave & 1) * 64, wn = (wave >> 1) * 64;
  ffrag acc[4][4];
  #pragma unroll
  for (int i = 0; i < 4; i++)
    #pragma unroll
    for (int j = 0; j < 4; j++) acc[i][j] = (ffrag){0.f,0.f,0.f,0.f};

  int srow = t >> 2;
  // bank-conflict-free swizzle (r13/r15: SQ_LDS_BANK_CONFLICT = 0, verified)
  int scol = ((((t & 3) - ((t >> 3) & 3)) & 3)) * 8;
  const bf16* gA = A  + (size_t)(bm + srow)*K + scol;
  const bf16* gB = Wt + (size_t)(bn + srow)*K + scol;
  char* lA = (char*)As + 16*t;
  char* lB = (char*)Bs + 16*t;
  int q = lane >> 4, r = lane & 15;
  int cs = (((q + (r >> 1)) & 3)) * 8;

  for (int k0 = 0; k0 < K; k0 += 32){
    gld16(gA + k0,          lA);
    gld16(gA + 64*K + k0,   lA + 4096);
    gld16(gB + k0,          lB);
    gld16(gB + 64*K + k0,   lB + 4096);
    __syncthreads();
    bfrag af[4], bfv[4];
    #pragma unroll
    for (int i = 0; i < 4; i++){
      af[i]  = *(const bfrag*)(As + (wm + i*16 + r)*32 + cs);
      bfv[i] = *(const bfrag*)(Bs + (wn + i*16 + r)*32 + cs);
    }
    #pragma unroll
    for (int i = 0; i < 4; i++)
      #pragma unroll
      for (int j = 0; j < 4; j++)
        acc[i][j] = __builtin_amdgcn_mfma_f32_16x16x32_bf16(af[i], bfv[j], acc[i][j], 0, 0, 0);
    __syncthreads();
  }
  #pragma unroll
  for (int i = 0; i < 4; i++){
    #pragma unroll
    for (int j = 0; j < 4; j++){
      int row = bm + wm + i*16 + q*4;
      int col = bn + wn + j*16 + r;
      const float* bp = (col < 512) ? b0 : (col < 1024) ? b1 :
                        (col < 1536) ? b2 : (col < 2048) ? b3 : b4;
      float bias = bp[col & 511];
      bf16* D; int ld;
      if (col < split){ D = D0 + (size_t)row*ld0 + col;         ld = ld0; }
      else            { D = D1 + (size_t)row*ld1 + (col-split); ld = ld1; }
      #pragma unroll
      for (int g = 0; g < 4; g++)
        D[(size_t)g*ld] = __float2bfloat16(acc[i][j][g] + bias);
    }
  }
}

// ---------------- logits GEMM: all 4 waves active, 32 rows each; cols<32 ----------------
__global__ __launch_bounds__(256) void k_logits(Params P){
  const int K = 512;
  __shared__ bf16 As[128*32];
  __shared__ bf16 Bs[128*32];
  int t = threadIdx.x;
  int wave = t >> 6, lane = t & 63;
  int bm = blockIdx.x * 128;
  int wm = wave * 32;                 // each wave owns 32 rows
  ffrag acc[2][2];
  #pragma unroll
  for (int i = 0; i < 2; i++){ acc[i][0] = (ffrag){0,0,0,0}; acc[i][1] = (ffrag){0,0,0,0}; }
  int srow = t >> 2;
  int scol = ((((t & 3) - ((t >> 3) & 3)) & 3)) * 8;
  const bf16* gA = P.ebf + (size_t)(bm + srow)*K + scol;   // hbf aliases ebf
  const bf16* gB = P.WtLog + (size_t)srow*K + scol;
  char* lA = (char*)As + 16*t;
  char* lB = (char*)Bs + 16*t;
  int q = lane >> 4, r = lane & 15;
  int cs = (((q + (r >> 1)) & 3)) * 8;

  for (int k0 = 0; k0 < K; k0 += 32){
    gld16(gA + k0,          lA);
    gld16(gA + 64*K + k0,   lA + 4096);
    gld16(gB + k0,          lB);
    gld16(gB + 64*K + k0,   lB + 4096);
    __syncthreads();
    bfrag bf0 = *(const bfrag*)(Bs + (r)*32 + cs);
    bfrag bf1 = *(const bfrag*)(Bs + (16 + r)*32 + cs);
    #pragma unroll
    for (int i = 0; i < 2; i++){
      bfrag af = *(const bfrag*)(As + (wm + i*16 + r)*32 + cs);
      acc[i][0] = __builtin_amdgcn_mfma_f32_16x16x32_bf16(af, bf0, acc[i][0], 0, 0, 0);
      acc[i][1] = __builtin_amdgcn_mfma_f32_16x16x32_bf16(af, bf1, acc[i][1], 0, 0, 0);
    }
    __syncthreads();
  }
  #pragma unroll
  for (int i = 0; i < 2; i++)
    #pragma unroll
    for (int j = 0; j < 2; j++){
      int row = bm + wm + i*16 + q*4;
      int col = j*16 + r;
      if (col < TT){
        float bv = P.ofc_b[col];
        #pragma unroll
        for (int g = 0; g < 4; g++)
          P.out[(size_t)(row + g)*TT + col] = acc[i][j][g] + bv;
      }
    }
}

// ---------------- sat attention: wave/token, us8 loads ----------------
__global__ __launch_bounds__(256)
void k_sat(Params P, const bf16* qp, int sq, const bf16* kp, const bf16* vp, int skv){
  int tok = blockIdx.x*4 + (threadIdx.x >> 6);
  int l = threadIdx.x & 63;
  int b = tok >> 9, li = tok & 511;
  int off = l*8;
  int t0 = (b << 9) | ((li + 1) & 511);
  int t2 = (b << 9) | (li == 0 ? 511 : 0);
  float qf[8];
  { us8 q8 = *(const us8*)(qp + (size_t)tok*sq + off);
    #pragma unroll
    for (int g = 0; g < 8; g++) qf[g] = us2f(q8[g]); }
  float sc[5];
  int rows[3] = {t0, tok, t2};
  #pragma unroll
  for (int j = 0; j < 3; j++){
    us8 k8 = *(const us8*)(kp + (size_t)rows[j]*skv + off);
    float a = 0.f;
    #pragma unroll
    for (int g = 0; g < 8; g++) a += qf[g]*us2f(k8[g]);
    sc[j] = hsum8(a) * 0.125f;
  }
  { us8 k8 = *(const us8*)(P.KeVe + (size_t)tok*1024 + off);
    float a = 0.f;
    #pragma unroll
    for (int g = 0; g < 8; g++) a += qf[g]*us2f(k8[g]);
    sc[3] = hsum8(a) * 0.125f; }
  { const float* ks = P.KsVs + (size_t)b*1024 + off;
    float4 f0 = *(const float4*)ks, f1 = *(const float4*)(ks + 4);
    float a = qf[0]*f0.x + qf[1]*f0.y + qf[2]*f0.z + qf[3]*f0.w
            + qf[4]*f1.x + qf[5]*f1.y + qf[6]*f1.z + qf[7]*f1.w;
    sc[4] = hsum8(a) * 0.125f; }
  float m = fmaxf(fmaxf(fmaxf(sc[0],sc[1]), fmaxf(sc[2],sc[3])), sc[4]);
  float pr[5], den = 0.f;
  #pragma unroll
  for (int j = 0; j < 5; j++){ pr[j] = __expf(sc[j]-m); den += pr[j]; }
  float inv = 1.0f/den;
  float o[8];
  #pragma unroll
  for (int g = 0; g < 8; g++) o[g] = 0.f;
  #pragma unroll
  for (int j = 0; j < 3; j++){
    us8 v8 = *(const us8*)(vp + (size_t)rows[j]*skv + off);
    #pragma unroll
    for (int g = 0; g < 8; g++) o[g] += pr[j]*us2f(v8[g]);
  }
  { us8 v8 = *(const us8*)(P.KeVe + (size_t)tok*1024 + 512 + off);
    #pragma unroll
    for (int g = 0; g < 8; g++) o[g] += pr[3]*us2f(v8[g]); }
  { const float* vs = P.KsVs + (size_t)b*1024 + 512 + off;
    float4 f0 = *(const float4*)vs, f1 = *(const float4*)(vs + 4);
    o[0] += pr[4]*f0.x; o[1] += pr[4]*f0.y; o[2] += pr[4]*f0.z; o[3] += pr[4]*f0.w;
    o[4] += pr[4]*f1.x; o[5] += pr[4]*f1.y; o[6] += pr[4]*f1.z; o[7] += pr[4]*f1.w; }
  bf16 ob[8];
  #pragma unroll
  for (int g = 0; g < 8; g++) ob[g] = __float2bfloat16(o[g]*inv);
  *(us8*)(P.ctxbf + (size_t)tok*DD + off) = *(const us8*)ob;
}

// ---------------- wave-per-row relu+LN (sat), bf16 ----------------
__global__ __launch_bounds__(256) void k_ln(Params P, const bf16* X, bf16* Y){
  int row = blockIdx.x*4 + (threadIdx.x >> 6);
  int lane = threadIdx.x & 63;
  int off = lane*8;
  us8 x8 = *(const us8*)(X + (size_t)row*DD + off);
  float v[8], sum = 0.f;
  #pragma unroll
  for (int g = 0; g < 8; g++){ v[g] = fmaxf(us2f(x8[g]), 0.f); sum += v[g]; }
  #pragma unroll
  for (int o = 32; o; o >>= 1) sum += __shfl_xor(sum, o);
  float u = sum * (1.0f/DD);
  float d[8], var = 0.f;
  #pragma unroll
  for (int g = 0; g < 8; g++){ d[g] = v[g] - u; var += d[g]*d[g]; }
  #pragma unroll
  for (int o = 32; o; o >>= 1) var += __shfl_xor(var, o);
  float inv = rsqrtf(var * (1.0f/DD) + 1e-12f);
  bf16 ob[8];
  #pragma unroll
  for (int g = 0; g < 8; g++)
    ob[g] = __float2bfloat16(P.ln_sat_w[off+g]*d[g]*inv + P.ln_sat_b[off+g]);
  *(us8*)(Y + (size_t)row*DD + off) = *(const us8*)ob;
}

// ---------------- rel attention partials ----------------
__global__ __launch_bounds__(256) void k_relp(Params P){
  __shared__ __align__(16) char sm[4096];
  int u = blockIdx.x, t = threadIdx.x;
  int ch = u & 7, hh = (u >> 3) & 7, b = u >> 6;
  float* qs   = (float*)sm;
  float* sc   = (float*)(sm + 256);
  float* red  = (float*)(sm + 1024);
  float (*part)[64] = (float(*)[64])(sm + 2048);
  int base = hh * HDD;
  int j0 = ch * RCK;
  int nk = min(513 - j0, RCK);
  if (t < 64) qs[t] = P.qr[(size_t)b*DD + base + t];
  __syncthreads();
  if (t < nk){
    int j = j0 + t;
    float a = 0.f;
    if (j == 0){
      const float* kr = P.Ksr + (size_t)b*DD + base;
      #pragma unroll
      for (int d = 0; d < 64; d += 4){
        float4 k4 = *(const float4*)(kr + d);
        float4 q4 = *(const float4*)(qs + d);
        a += q4.x*k4.x + q4.y*k4.y + q4.z*k4.z + q4.w*k4.w;
      }
    } else {
      const bf16* kr = P.kvbuf + ((size_t)b*LL + j - 1)*1024 + base;
      #pragma unroll
      for (int d = 0; d < 64; d += 8){
        us8 k8 = *(const us8*)(kr + d);
        #pragma unroll
        for (int g = 0; g < 8; g++) a += qs[d+g] * us2f(k8[g]);
      }
    }
    sc[t] = a * 0.125f;
  }
  __syncthreads();
  red[t] = (t < nk) ? sc[t] : -1e30f; __syncthreads();
  for (int st = 128; st; st >>= 1){ if (t < st) red[t] = fmaxf(red[t], red[t+st]); __syncthreads(); }
  float m = red[0]; __syncthreads();
  if (t < nk) sc[t] = __expf(sc[t] - m);
  __syncthreads();
  red[t] = (t < nk) ? sc[t] : 0.f; __syncthreads();
  for (int st = 128; st; st >>= 1){ if (t < st) red[t] += red[t+st]; __syncthreads(); }
  float l = red[0];
  int d = t & 63, c2 = t >> 6;
  float a = 0.f;
  for (int j = c2; j < nk; j += 4){
    int gj = j0 + j;
    float vv = (gj == 0) ? P.Vsr[(size_t)b*DD + base + d]
                         : __bfloat162float(P.kvbuf[((size_t)b*LL + gj - 1)*1024 + 512 + base + d]);
    a += sc[j] * vv;
  }
  part[c2][d] = a; __syncthreads();
  float* o = P.pws + (((size_t)(b*NHH + hh))*RCH + ch) * 66;
  if (t < 64) o[t] = part[0][t] + part[1][t] + part[2][t] + part[3][t];
  else if (t == 64) o[64] = m;
  else if (t == 65) o[65] = l;
}

// ---------------- rel tail pass A: combine + split-k out-proj (256 blocks) ----------------
__global__ __launch_bounds__(256) void k_reltail2(Params P){
  __shared__ float crs[512];
  __shared__ float part[8][33];
  int b = blockIdx.x >> 4, ch = blockIdx.x & 15;
  int t = threadIdx.x;
  for (int o = t; o < 512; o += 256){
    int hh = o >> 6, d = o & 63;
    const float* p = P.pws + ((size_t)(b*NHH + hh))*RCH*66;
    float M = -1e30f;
    #pragma unroll
    for (int c = 0; c < RCH; c++) M = fmaxf(M, p[c*66 + 64]);
    float den = 0.f, acc = 0.f;
    #pragma unroll
    for (int c = 0; c < RCH; c++){
      float w = __expf(p[c*66 + 64] - M);
      den += w * p[c*66 + 65];
      acc += w * p[c*66 + d];
    }
    crs[o] = acc / den;
  }
  __syncthreads();
  int n = t & 31, kg = t >> 5;
  int col = ch*32 + n;
  const float* Wp = P.rel_ow + (size_t)(kg*64)*512 + col;
  const float* cp = crs + kg*64;
  float a = 0.f;
  for (int k = 0; k < 64; k++) a = fmaf(cp[k], Wp[(size_t)k*512], a);
  part[kg][n] = a;
  __syncthreads();
  if (t < 32){
    float v = P.rel_ob[ch*32 + t];
    #pragma unroll
    for (int g = 0; g < 8; g++) v += part[g][t];
    P.qr[(size_t)b*DD + ch*32 + t] = v;   // rr aliases qr
  }
}

// ---------------- rel tail pass B: relu+LN (fp32, wave-per-row) -> s ----------------
__global__ __launch_bounds__(256) void k_lnrel(Params P){
  int row = blockIdx.x*4 + (threadIdx.x >> 6);   // 4 blocks x 4 rows
  int lane = threadIdx.x & 63;
  int off = lane*8;
  const float* x = P.qr + (size_t)row*DD + off;
  float4 f0 = *(const float4*)x, f1 = *(const float4*)(x + 4);
  float v[8] = {f0.x, f0.y, f0.z, f0.w, f1.x, f1.y, f1.z, f1.w};
  float sum = 0.f;
  #pragma unroll
  for (int g = 0; g < 8; g++){ v[g] = fmaxf(v[g], 0.f); sum += v[g]; }
  #pragma unroll
  for (int o = 32; o; o >>= 1) sum += __shfl_xor(sum, o);
  float u = sum * (1.0f/DD);
  float d[8], var = 0.f;
  #pragma unroll
  for (int g = 0; g < 8; g++){ d[g] = v[g] - u; var += d[g]*d[g]; }
  #pragma unroll
  for (int o = 32; o; o >>= 1) var += __shfl_xor(var, o);
  float inv = rsqrtf(var * (1.0f/DD) + 1e-12f);
  // s MUST be written — feeds the c1 KsVs projection (round-5 lesson).
  #pragma unroll
  for (int g = 0; g < 8; g++)
    P.s[(size_t)row*DD + off + g] = P.ln_rel_w[off+g]*d[g]*inv + P.ln_rel_b[off+g];
}

extern "C" void kernel_launch(void* const* d_in, const int* in_sizes, int n_in,
                              void* d_out, int out_size, void* d_ws, size_t ws_size,
                              hipStream_t stream) {
  Params P;
  P.tokens  = (const int*)  d_in[0];
  P.emb     = (const float*)d_in[4];
  P.sat_qw  = (const float*)d_in[5];  P.sat_qb = (const float*)d_in[6];
  P.sat_kw  = (const float*)d_in[7];  P.sat_kb = (const float*)d_in[8];
  P.sat_vw  = (const float*)d_in[9];  P.sat_vb = (const float*)d_in[10];
  P.sat_ow  = (const float*)d_in[11]; P.sat_ob = (const float*)d_in[12];
  P.rel_qw  = (const float*)d_in[13]; P.rel_qb = (const float*)d_in[14];
  P.rel_kw  = (const float*)d_in[15]; P.rel_kb = (const float*)d_in[16];
  P.rel_vw  = (const float*)d_in[17]; P.rel_vb = (const float*)d_in[18];
  P.rel_ow  = (const float*)d_in[19]; P.rel_ob = (const float*)d_in[20];
  P.ln_sat_w= (const float*)d_in[21]; P.ln_sat_b= (const float*)d_in[22];
  P.ln_rel_w= (const float*)d_in[23]; P.ln_rel_b= (const float*)d_in[24];
  P.ofc_w   = (const float*)d_in[25]; P.ofc_b  = (const float*)d_in[26];

  char* p = (char*)d_ws;
  auto alloc = [&](size_t bytes) -> char* {
    char* r = p; p += (bytes + 255) & ~(size_t)255; return r;
  };
  const size_t BIGH = (size_t)MM*DD*2;
  P.ebf   = (bf16*) alloc(BIGH);
  P.qkv   = (bf16*) alloc(3*BIGH);
  P.kvbuf = (bf16*) alloc(2*BIGH);
  P.KeVe  = (bf16*) alloc(2*BIGH);
  P.qbuf  = (bf16*) alloc(BIGH);
  P.ctxbf = (bf16*) alloc(BIGH);
  P.WtAll = (bf16*) alloc((size_t)2560*512*2);
  P.WtO   = (bf16*) alloc((size_t)512*512*2);
  P.WtLog = (bf16*) alloc((size_t)128*512*2);
  P.s     = (float*)alloc(BB*DD*4);
  P.KsVs  = (float*)alloc(BB*1024*4);
  P.qr    = (float*)alloc(BB*DD*4);
  P.Ksr   = (float*)alloc(BB*DD*4);
  P.Vsr   = (float*)alloc(BB*DD*4);
  P.mpart = (float*)alloc((size_t)256*DD*4);
  P.pws   = (float*)alloc((size_t)BB*NHH*RCH*66*4);
  P.out   = (float*)d_out;

  bf16* hbf  = P.ebf;   // h aliases e
  bf16* aout = P.qkv;   // out-proj scratch aliases qkv

  // 15 launches; no grid.sync (r13); no long-serial blocks (r14);
  // GEMM bodies standalone (r16 VGPR lesson); mean fused into sproj0 (r18).
  k_init<<<2048, 256, 0, stream>>>(P);
  k_sproj0<<<80, 256, 0, stream>>>(P);
  k_gemm<<<768, 256, 0, stream>>>(P, P.ebf, P.WtAll,
      P.sat_qb, P.sat_kb, P.sat_vb, P.sat_vb, P.sat_vb, P.qbuf, 512, P.KeVe, 1024, 512);
  k_sat<<<MM/4, 256, 0, stream>>>(P, P.qbuf, 512, P.KeVe, P.KeVe + 512, 1024);
  k_gemm<<<256, 256, 0, stream>>>(P, P.ctxbf, P.WtO,
      P.sat_ob, P.sat_ob, P.sat_ob, P.sat_ob, P.sat_ob, aout, 512, aout, 512, 512);
  k_ln<<<MM/4, 256, 0, stream>>>(P, aout, hbf);
  k_gemm<<<1280, 256, 0, stream>>>(P, hbf, P.WtAll,
      P.sat_qb, P.sat_kb, P.sat_vb, P.rel_kb, P.rel_vb, P.qkv, 1536, P.kvbuf, 1024, 1536);
  k_relp<<<BB*NHH*RCH, 256, 0, stream>>>(P);
  k_reltail2<<<256, 256, 0, stream>>>(P);
  k_lnrel<<<4, 256, 0, stream>>>(P);
  k_sproj1<<<32, 256, 0, stream>>>(P);
  k_sat<<<MM/4, 256, 0, stream>>>(P, P.qkv, 1536, P.qkv + 512, P.qkv + 1024, 1536);
  k_gemm<<<256, 256, 0, stream>>>(P, P.ctxbf, P.WtO,
      P.sat_ob, P.sat_ob, P.sat_ob, P.sat_ob, P.sat_ob, aout, 512, aout, 512, 512);
  k_ln<<<MM/4, 256, 0, stream>>>(P, aout, hbf);
  k_logits<<<64, 256, 0, stream>>>(P);
}